// Round 2
// baseline (76.945 us; speedup 1.0000x reference)
//
#include <hip/hip_runtime.h>
#include <math.h>

// MultiAttention: T=5, D=32, H=4, hd=8. One fused kernel, one workgroup.
// All tensors are fp32 (reference uses jnp.float32; round-1 NaN proved the
// buffers are NOT bf16 — reading f32 as bf16 injected NaN bit patterns).

#define CTX 5
#define DIM 32
#define NH  4
#define HD  8

__launch_bounds__(256, 1)
__global__ void mha_fused_kernel(
    const float* __restrict__ X,
    const float* __restrict__ WQ,
    const float* __restrict__ WK,
    const float* __restrict__ WV,
    const float* __restrict__ Wp,
    const float* __restrict__ bp,
    const float* __restrict__ W1,
    const float* __restrict__ b1,
    const float* __restrict__ W2,
    const float* __restrict__ b2,
    float* __restrict__ out)
{
    __shared__ float sX[CTX][DIM];
    __shared__ float sW[6][DIM][DIM];       // WQ WK WV Wp W1 W2 (row-major, W[i][c])
    __shared__ float sQ[CTX][DIM];
    __shared__ float sK[CTX][DIM];
    __shared__ float sV[CTX][DIM];
    __shared__ float sS[NH][CTX][CTX];      // softmax probs
    __shared__ float sY[CTX][DIM];          // attention output (concat heads)
    __shared__ float sYp[CTX][DIM];         // Yproj (+bias)
    __shared__ float sH1[CTX][DIM];         // relu hidden

    const int tid = threadIdx.x;

    // ---- stage inputs to LDS ----
    if (tid < CTX * DIM) sX[tid / DIM][tid % DIM] = X[tid];
    const float* ws[6] = { WQ, WK, WV, Wp, W1, W2 };
    #pragma unroll
    for (int m = 0; m < 6; ++m)
        for (int idx = tid; idx < DIM * DIM; idx += 256)
            sW[m][idx / DIM][idx % DIM] = ws[m][idx];
    __syncthreads();

    // ---- QKV projections: thread (t,i), tid<160 ----
    if (tid < CTX * DIM) {
        const int t = tid / DIM, i = tid % DIM;
        float q = 0.f, k = 0.f, v = 0.f;
        #pragma unroll
        for (int c = 0; c < DIM; ++c) {
            const float x = sX[t][c];
            q += x * sW[0][i][c];
            k += x * sW[1][i][c];
            v += x * sW[2][i][c];
        }
        sQ[t][i] = q; sK[t][i] = k; sV[t][i] = v;
    }
    __syncthreads();

    // ---- scores + causal softmax: one thread per (h,q) ----
    if (tid < NH * CTX) {
        const int h = tid / CTX, q = tid % CTX;
        float sc[CTX];
        float mx = -1e30f;
        #pragma unroll
        for (int k = 0; k < CTX; ++k) {
            float s = 0.f;
            #pragma unroll
            for (int d = 0; d < HD; ++d)
                s += sQ[q][h * HD + d] * sK[k][h * HD + d];
            s *= 0.17677669529663687f;      // 1/sqrt(DIM) (source scales by sqrt(DIM))
            if (k > q) s = -1e30f;          // causal mask
            sc[k] = s;
            mx = fmaxf(mx, s);
        }
        float sum = 0.f;
        #pragma unroll
        for (int k = 0; k < CTX; ++k) { sc[k] = expf(sc[k] - mx); sum += sc[k]; }
        const float inv = 1.0f / sum;
        #pragma unroll
        for (int k = 0; k < CTX; ++k) sS[h][q][k] = sc[k] * inv;
    }
    __syncthreads();

    // ---- Y = S @ V (per-head), concat heads: thread (t,i) ----
    if (tid < CTX * DIM) {
        const int t = tid / DIM, i = tid % DIM;
        const int h = i / HD;
        float y = 0.f;
        #pragma unroll
        for (int k = 0; k < CTX; ++k) y += sS[h][t][k] * sV[k][i];
        sY[t][i] = y;
    }
    __syncthreads();

    // ---- Yproj = Y @ Wp^T + bp ----
    if (tid < CTX * DIM) {
        const int t = tid / DIM, i = tid % DIM;
        float acc = bp[i];
        #pragma unroll
        for (int c = 0; c < DIM; ++c) acc += sY[t][c] * sW[3][i][c];
        sYp[t][i] = acc;
    }
    __syncthreads();

    // ---- H1 = relu(Yproj @ W1^T + b1) ----
    if (tid < CTX * DIM) {
        const int t = tid / DIM, i = tid % DIM;
        float acc = b1[i];
        #pragma unroll
        for (int c = 0; c < DIM; ++c) acc += sYp[t][c] * sW[4][i][c];
        sH1[t][i] = fmaxf(acc, 0.f);
    }
    __syncthreads();

    // ---- Y2 = H1 @ W2^T + b2 ; out = Y2 + Yproj ----
    if (tid < CTX * DIM) {
        const int t = tid / DIM, i = tid % DIM;
        float acc = b2[i];
        #pragma unroll
        for (int c = 0; c < DIM; ++c) acc += sH1[t][c] * sW[5][i][c];
        out[tid] = acc + sYp[t][i];
    }
}

extern "C" void kernel_launch(void* const* d_in, const int* in_sizes, int n_in,
                              void* d_out, int out_size, void* d_ws, size_t ws_size,
                              hipStream_t stream) {
    (void)in_sizes; (void)n_in; (void)out_size; (void)d_ws; (void)ws_size;
    const float* X  = (const float*)d_in[0];
    const float* WQ = (const float*)d_in[1];
    const float* WK = (const float*)d_in[2];
    const float* WV = (const float*)d_in[3];
    const float* Wp = (const float*)d_in[4];
    const float* bp = (const float*)d_in[5];
    const float* W1 = (const float*)d_in[6];
    const float* b1 = (const float*)d_in[7];
    const float* W2 = (const float*)d_in[8];
    const float* b2 = (const float*)d_in[9];
    float* out = (float*)d_out;

    mha_fused_kernel<<<1, 256, 0, stream>>>(X, WQ, WK, WV, Wp, bp, W1, b1, W2, b2, out);
}

// Round 3
// 75.870 us; speedup vs baseline: 1.0142x; 1.0142x over previous
//
#include <hip/hip_runtime.h>
#include <math.h>

// MultiAttention: T=5, D=32, H=4, hd=8. One fused kernel, one workgroup, fp32.
// R3 change: drop the 6-matrix LDS staging phase (weights have only 5x reuse;
// read them straight from global / L1), stage X via float4, one fewer barrier.
// A/B probe: if dur_us is unchanged, the timed region is the harness's 0xAA
// workspace poison fills (2 x 39 us at 86% HBM peak) and we are at the floor.

#define CTX 5
#define DIM 32
#define NH  4
#define HD  8

__launch_bounds__(256, 1)
__global__ void mha_fused_kernel(
    const float* __restrict__ X,
    const float* __restrict__ WQ,
    const float* __restrict__ WK,
    const float* __restrict__ WV,
    const float* __restrict__ Wp,
    const float* __restrict__ bp,
    const float* __restrict__ W1,
    const float* __restrict__ b1,
    const float* __restrict__ W2,
    const float* __restrict__ b2,
    float* __restrict__ out)
{
    __shared__ float sX[CTX][DIM];
    __shared__ float sQ[CTX][DIM];
    __shared__ float sK[CTX][DIM];
    __shared__ float sV[CTX][DIM];
    __shared__ float sS[NH][CTX][CTX];
    __shared__ float sY[CTX][DIM];
    __shared__ float sYp[CTX][DIM];
    __shared__ float sH1[CTX][DIM];

    const int tid = threadIdx.x;

    // ---- stage X to LDS as float4 (160 floats = 40 float4) ----
    if (tid < CTX * DIM / 4)
        ((float4*)&sX[0][0])[tid] = ((const float4*)X)[tid];
    __syncthreads();

    // ---- QKV projections: thread (t,i), weights straight from global ----
    if (tid < CTX * DIM) {
        const int t = tid / DIM, i = tid % DIM;
        const float* wq = WQ + i * DIM;
        const float* wk = WK + i * DIM;
        const float* wv = WV + i * DIM;
        float q = 0.f, k = 0.f, v = 0.f;
        #pragma unroll
        for (int c = 0; c < DIM; ++c) {
            const float x = sX[t][c];
            q += x * wq[c];
            k += x * wk[c];
            v += x * wv[c];
        }
        sQ[t][i] = q; sK[t][i] = k; sV[t][i] = v;
    }
    __syncthreads();

    // ---- scores + causal softmax: one thread per (h,q) ----
    if (tid < NH * CTX) {
        const int h = tid / CTX, q = tid % CTX;
        float sc[CTX];
        float mx = -1e30f;
        #pragma unroll
        for (int k = 0; k < CTX; ++k) {
            float s = 0.f;
            #pragma unroll
            for (int d = 0; d < HD; ++d)
                s += sQ[q][h * HD + d] * sK[k][h * HD + d];
            s *= 0.17677669529663687f;      // 1/sqrt(DIM) (source scales by sqrt(DIM))
            if (k > q) s = -1e30f;          // causal mask
            sc[k] = s;
            mx = fmaxf(mx, s);
        }
        float sum = 0.f;
        #pragma unroll
        for (int k = 0; k < CTX; ++k) { sc[k] = expf(sc[k] - mx); sum += sc[k]; }
        const float inv = 1.0f / sum;
        #pragma unroll
        for (int k = 0; k < CTX; ++k) sS[h][q][k] = sc[k] * inv;
    }
    __syncthreads();

    // ---- Y = S @ V (per-head), concat heads ----
    if (tid < CTX * DIM) {
        const int t = tid / DIM, i = tid % DIM;
        const int h = i / HD;
        float y = 0.f;
        #pragma unroll
        for (int k = 0; k < CTX; ++k) y += sS[h][t][k] * sV[k][i];
        sY[t][i] = y;
    }
    __syncthreads();

    // ---- Yproj = Y @ Wp^T + bp ----
    if (tid < CTX * DIM) {
        const int t = tid / DIM, i = tid % DIM;
        const float* wp = Wp + i * DIM;
        float acc = bp[i];
        #pragma unroll
        for (int c = 0; c < DIM; ++c) acc += sY[t][c] * wp[c];
        sYp[t][i] = acc;
    }
    __syncthreads();

    // ---- H1 = relu(Yproj @ W1^T + b1) ----
    if (tid < CTX * DIM) {
        const int t = tid / DIM, i = tid % DIM;
        const float* w1 = W1 + i * DIM;
        float acc = b1[i];
        #pragma unroll
        for (int c = 0; c < DIM; ++c) acc += sYp[t][c] * w1[c];
        sH1[t][i] = fmaxf(acc, 0.f);
    }
    __syncthreads();

    // ---- Y2 = H1 @ W2^T + b2 ; out = Y2 + Yproj ----
    if (tid < CTX * DIM) {
        const int t = tid / DIM, i = tid % DIM;
        const float* w2 = W2 + i * DIM;
        float acc = b2[i];
        #pragma unroll
        for (int c = 0; c < DIM; ++c) acc += sH1[t][c] * w2[c];
        out[tid] = acc + sYp[t][i];
    }
}

extern "C" void kernel_launch(void* const* d_in, const int* in_sizes, int n_in,
                              void* d_out, int out_size, void* d_ws, size_t ws_size,
                              hipStream_t stream) {
    (void)in_sizes; (void)n_in; (void)out_size; (void)d_ws; (void)ws_size;
    const float* X  = (const float*)d_in[0];
    const float* WQ = (const float*)d_in[1];
    const float* WK = (const float*)d_in[2];
    const float* WV = (const float*)d_in[3];
    const float* Wp = (const float*)d_in[4];
    const float* bp = (const float*)d_in[5];
    const float* W1 = (const float*)d_in[6];
    const float* b1 = (const float*)d_in[7];
    const float* W2 = (const float*)d_in[8];
    const float* b2 = (const float*)d_in[9];
    float* out = (float*)d_out;

    mha_fused_kernel<<<1, 256, 0, stream>>>(X, WQ, WK, WV, Wp, bp, W1, b1, W2, b2, out);
}